// Round 1
// baseline (462.170 us; speedup 1.0000x reference)
//
#include <hip/hip_runtime.h>

// Problem constants (from reference setup_inputs)
constexpr int MP  = 10242;  // coarse vertices (output rows)
constexpr int B   = 16;     // batch
constexpr int M   = 40962;  // fine vertices
constexpr int F   = 128;    // features
constexpr int CAP = 32;     // ELL capacity per row; counts ~Poisson(4), P(>32) ~ 1e-18

typedef float f32x4 __attribute__((ext_vector_type(4)));

// ---------------------------------------------------------------------------
// Build ELL: one pass. counts[] doubles as the insertion cursor.
// Entries packed as {col, bitcast(val)} so the pool reads one 8B scalar load.
__global__ void build_ell_kernel(const int* __restrict__ rows,
                                 const int* __restrict__ cols,
                                 const float* __restrict__ vals,
                                 int* __restrict__ counts,   // [MP], pre-zeroed
                                 int2* __restrict__ ell,     // [MP*CAP]
                                 int nnz) {
    int k = blockIdx.x * blockDim.x + threadIdx.x;
    if (k < nnz) {
        int p = rows[k];
        int slot = atomicAdd(&counts[p], 1);
        if (slot < CAP) {                 // safety clamp; never triggers at Poisson(4)
            ell[p * CAP + slot] = make_int2(cols[k], __float_as_int(vals[k]));
        }
    }
}

// ---------------------------------------------------------------------------
// Pool: block = one coarse vertex p (blockIdx.x), so ALL metadata addressing
// is block-uniform -> scalar loads (s_load), vals feed FMAs as SGPR operands.
// Each wave covers 4 batch slices: (bA, bA+1) via lane halves, and (bA+8,
// bA+9) interleaved in the same j-loop -> 8 x 1KB gather loads in flight.
__global__ __launch_bounds__(256)
void pool_kernel(const float4* __restrict__ x,
                 const int* __restrict__ counts,
                 const int2* __restrict__ ell,
                 float4* __restrict__ out) {
    const int p    = blockIdx.x;            // coarse vertex (block-uniform)
    const int q    = threadIdx.x >> 6;      // wave id in block, [0,4)
    const int lane = threadIdx.x & 63;
    const int half = lane >> 5;             // which batch of the pair
    const int l    = lane & 31;             // float4 index within feature row

    const int bA = (q << 1) | half;         // slices 0..7
    const int bB = bA + 8;                  // slices 8..15

    int n = counts[p];
    n = n < CAP ? n : CAP;
    const int2* pe = ell + p * CAP;
    const float4* xA = x + (size_t)bA * (M * (F / 4));
    const float4* xB = x + (size_t)bB * (M * (F / 4));

    float4 accA; accA.x = accA.y = accA.z = accA.w = 0.f;
    float4 accB; accB.x = accB.y = accB.z = accB.w = 0.f;

    int j = 0;
    for (; j + 4 <= n; j += 4) {
        int2 e0 = pe[j], e1 = pe[j + 1], e2 = pe[j + 2], e3 = pe[j + 3];
        // 8 independent 1KB vector loads in flight before any FMA
        float4 a0 = xA[(size_t)e0.x * (F / 4) + l];
        float4 a1 = xA[(size_t)e1.x * (F / 4) + l];
        float4 a2 = xA[(size_t)e2.x * (F / 4) + l];
        float4 a3 = xA[(size_t)e3.x * (F / 4) + l];
        float4 c0 = xB[(size_t)e0.x * (F / 4) + l];
        float4 c1 = xB[(size_t)e1.x * (F / 4) + l];
        float4 c2 = xB[(size_t)e2.x * (F / 4) + l];
        float4 c3 = xB[(size_t)e3.x * (F / 4) + l];
        float v0 = __int_as_float(e0.y), v1 = __int_as_float(e1.y);
        float v2 = __int_as_float(e2.y), v3 = __int_as_float(e3.y);
        accA.x = fmaf(v0, a0.x, fmaf(v1, a1.x, fmaf(v2, a2.x, fmaf(v3, a3.x, accA.x))));
        accA.y = fmaf(v0, a0.y, fmaf(v1, a1.y, fmaf(v2, a2.y, fmaf(v3, a3.y, accA.y))));
        accA.z = fmaf(v0, a0.z, fmaf(v1, a1.z, fmaf(v2, a2.z, fmaf(v3, a3.z, accA.z))));
        accA.w = fmaf(v0, a0.w, fmaf(v1, a1.w, fmaf(v2, a2.w, fmaf(v3, a3.w, accA.w))));
        accB.x = fmaf(v0, c0.x, fmaf(v1, c1.x, fmaf(v2, c2.x, fmaf(v3, c3.x, accB.x))));
        accB.y = fmaf(v0, c0.y, fmaf(v1, c1.y, fmaf(v2, c2.y, fmaf(v3, c3.y, accB.y))));
        accB.z = fmaf(v0, c0.z, fmaf(v1, c1.z, fmaf(v2, c2.z, fmaf(v3, c3.z, accB.z))));
        accB.w = fmaf(v0, c0.w, fmaf(v1, c1.w, fmaf(v2, c2.w, fmaf(v3, c3.w, accB.w))));
    }
    for (; j < n; ++j) {
        int2 e = pe[j];
        float v = __int_as_float(e.y);
        float4 a = xA[(size_t)e.x * (F / 4) + l];
        float4 c = xB[(size_t)e.x * (F / 4) + l];
        accA.x = fmaf(v, a.x, accA.x);
        accA.y = fmaf(v, a.y, accA.y);
        accA.z = fmaf(v, a.z, accA.z);
        accA.w = fmaf(v, a.w, accA.w);
        accB.x = fmaf(v, c.x, accB.x);
        accB.y = fmaf(v, c.y, accB.y);
        accB.z = fmaf(v, c.z, accB.z);
        accB.w = fmaf(v, c.w, accB.w);
    }

    // Non-temporal stores: out (84MB) is never re-read; keep L2/L3 for x.
    float4* oA = out + ((size_t)bA * MP + p) * (F / 4) + l;
    float4* oB = out + ((size_t)bB * MP + p) * (F / 4) + l;
    __builtin_nontemporal_store(*(const f32x4*)&accA, (f32x4*)oA);
    __builtin_nontemporal_store(*(const f32x4*)&accB, (f32x4*)oB);
}

// ---------------------------------------------------------------------------
extern "C" void kernel_launch(void* const* d_in, const int* in_sizes, int n_in,
                              void* d_out, int out_size, void* d_ws, size_t ws_size,
                              hipStream_t stream) {
    const float* x    = (const float*)d_in[0];
    const int*   rows = (const int*)d_in[1];
    const int*   cols = (const int*)d_in[2];
    const float* vals = (const float*)d_in[3];
    float* out = (float*)d_out;
    const int nnz = in_sizes[1];

    // Workspace: counts[MP] | ell[MP*CAP] (int2)
    int*  counts = (int*)d_ws;
    int2* ell    = (int2*)(counts + MP);   // MP*4 = 40968 bytes, 8B-aligned

    hipMemsetAsync(counts, 0, MP * sizeof(int), stream);

    int nb = (nnz + 255) / 256;
    build_ell_kernel<<<nb, 256, 0, stream>>>(rows, cols, vals, counts, ell, nnz);

    // One block per coarse vertex; 4 waves = 16 batch slices (4 per wave)
    pool_kernel<<<MP, 256, 0, stream>>>((const float4*)x, counts, ell, (float4*)out);
}